// Round 1
// baseline (549.678 us; speedup 1.0000x reference)
//
#include <hip/hip_runtime.h>
#include <hip/hip_bf16.h>
#include <math.h>

#define B_SZ 16384
#define DENSE 64
#define N_OH 8
#define N_MH 4
#define VOCAB 100000
#define EMB 32
#define HIST 20
#define IN_DIM 448
#define HID1 1024
#define HID2 512
#define HID3 256
#define CROSS_ORDER 4

// ---------------- embedding + concat -> x0 (B x 448) ----------------
// one wave (64 lanes) per row; 4 waves per block
__global__ __launch_bounds__(256) void embed_kernel(
    const float* __restrict__ dense, const int* __restrict__ oh_idx,
    const int* __restrict__ mh_idx, const float* __restrict__ oh_emb,
    const float* __restrict__ mh_emb, float* __restrict__ x0) {
  int wave = (blockIdx.x * blockDim.x + threadIdx.x) >> 6;
  int lane = threadIdx.x & 63;
  if (wave >= B_SZ) return;
  int row = wave;
  float* xr = x0 + (size_t)row * IN_DIM;
  // dense: 64 elements, one per lane
  xr[lane] = dense[(size_t)row * DENSE + lane];
  // one-hot: 8 fields x 32 = 256 elements, 4 per lane
#pragma unroll
  for (int r = 0; r < 4; ++r) {
    int e = lane + r * 64;
    int f = e >> 5, d = e & 31;
    int idx = oh_idx[row * N_OH + f];
    xr[64 + e] = oh_emb[((size_t)f * VOCAB + idx) * EMB + d];
  }
  // multi-hot sum-pool: 4 fields x 32 = 128 elements, 2 per lane
#pragma unroll
  for (int r = 0; r < 2; ++r) {
    int e = lane + r * 64;
    int f = e >> 5, d = e & 31;
    const int* hist = mh_idx + ((size_t)row * N_MH + f) * HIST;
    float s = 0.f;
#pragma unroll
    for (int j = 0; j < HIST; ++j) {
      s += mh_emb[((size_t)f * VOCAB + hist[j]) * EMB + d];
    }
    xr[320 + e] = s;
  }
}

// ---------------- cross net: xi = x0*(xi.w_l) + b_l + xi, 4 layers ----------------
// one wave per row; 7 elements per lane (448 = 7*64), stride-64 layout
__global__ __launch_bounds__(256) void cross_kernel(
    const float* __restrict__ x0g, const float* __restrict__ cw,
    const float* __restrict__ cb, float* __restrict__ xig) {
  int wave = (blockIdx.x * blockDim.x + threadIdx.x) >> 6;
  int lane = threadIdx.x & 63;
  if (wave >= B_SZ) return;
  const float* xr = x0g + (size_t)wave * IN_DIM;
  float x0v[7], xiv[7];
#pragma unroll
  for (int r = 0; r < 7; ++r) {
    x0v[r] = xr[lane + r * 64];
    xiv[r] = x0v[r];
  }
  for (int l = 0; l < CROSS_ORDER; ++l) {
    const float* w = cw + l * IN_DIM;
    const float* b = cb + l * IN_DIM;
    float dot = 0.f;
#pragma unroll
    for (int r = 0; r < 7; ++r) dot += xiv[r] * w[lane + r * 64];
#pragma unroll
    for (int s = 32; s > 0; s >>= 1) dot += __shfl_xor(dot, s);
#pragma unroll
    for (int r = 0; r < 7; ++r) xiv[r] = x0v[r] * dot + b[lane + r * 64] + xiv[r];
  }
  float* xo = xig + (size_t)wave * IN_DIM;
#pragma unroll
  for (int r = 0; r < 7; ++r) xo[lane + r * 64] = xiv[r];
}

// ---------------- fp32 tiled GEMM: C = relu?(A[MxK] @ W[KxN] + bias) ----------------
// 64x64 tile, BK=16, 256 threads, 4x4 micro-tile per thread
template <bool RELU>
__global__ __launch_bounds__(256) void gemm_kernel(
    const float* __restrict__ A, const float* __restrict__ W,
    const float* __restrict__ bias, float* __restrict__ C, int M, int N, int K) {
  __shared__ float As[16][64];
  __shared__ float Bs[16][64];
  const int tid = threadIdx.x;
  const int tx = tid & 15;       // N direction (16 threads)
  const int ty = tid >> 4;       // M direction (16 threads)
  const int n0 = blockIdx.x * 64;
  const int row0 = blockIdx.y * 64;

  // A-load mapping: m = tid>>2 (0..63), kq = (tid&3)*4
  const int am = tid >> 2;
  const int akq = (tid & 3) * 4;
  // B-load mapping: k = tid>>4 (0..15), nq = (tid&15)*4
  const int bk = tid >> 4;
  const int bnq = (tid & 15) * 4;

  float acc[4][4];
#pragma unroll
  for (int i = 0; i < 4; ++i)
#pragma unroll
    for (int j = 0; j < 4; ++j) acc[i][j] = 0.f;

  for (int k0 = 0; k0 < K; k0 += 16) {
    float4 av = *reinterpret_cast<const float4*>(&A[(size_t)(row0 + am) * K + k0 + akq]);
    float4 bv = *reinterpret_cast<const float4*>(&W[(size_t)(k0 + bk) * N + n0 + bnq]);
    __syncthreads();
    As[akq + 0][am] = av.x;
    As[akq + 1][am] = av.y;
    As[akq + 2][am] = av.z;
    As[akq + 3][am] = av.w;
    *reinterpret_cast<float4*>(&Bs[bk][bnq]) = bv;
    __syncthreads();
#pragma unroll
    for (int k = 0; k < 16; ++k) {
      float a[4], b[4];
#pragma unroll
      for (int i = 0; i < 4; ++i) a[i] = As[k][ty * 4 + i];
#pragma unroll
      for (int j = 0; j < 4; ++j) b[j] = Bs[k][tx * 4 + j];
#pragma unroll
      for (int i = 0; i < 4; ++i)
#pragma unroll
        for (int j = 0; j < 4; ++j) acc[i][j] = fmaf(a[i], b[j], acc[i][j]);
    }
  }
#pragma unroll
  for (int i = 0; i < 4; ++i) {
    int row = row0 + ty * 4 + i;
#pragma unroll
    for (int j = 0; j < 4; ++j) {
      int col = n0 + tx * 4 + j;
      float v = acc[i][j] + bias[col];
      if (RELU) v = fmaxf(v, 0.f);
      C[(size_t)row * N + col] = v;
    }
  }
}

// ---------------- final head: sigmoid(concat(xi, h3) @ lin_w + lin_b) ----------------
__global__ __launch_bounds__(256) void final_kernel(
    const float* __restrict__ xi, const float* __restrict__ h3,
    const float* __restrict__ lw, const float* __restrict__ lb,
    float* __restrict__ out) {
  int wave = (blockIdx.x * blockDim.x + threadIdx.x) >> 6;
  int lane = threadIdx.x & 63;
  if (wave >= B_SZ) return;
  float s = 0.f;
  const float* xr = xi + (size_t)wave * IN_DIM;
#pragma unroll
  for (int r = 0; r < 7; ++r) s += xr[lane + r * 64] * lw[lane + r * 64];
  const float* hr = h3 + (size_t)wave * HID3;
#pragma unroll
  for (int r = 0; r < 4; ++r) s += hr[lane + r * 64] * lw[448 + lane + r * 64];
#pragma unroll
  for (int t = 32; t > 0; t >>= 1) s += __shfl_xor(s, t);
  if (lane == 0) out[wave] = 1.f / (1.f + expf(-(s + lb[0])));
}

extern "C" void kernel_launch(void* const* d_in, const int* in_sizes, int n_in,
                              void* d_out, int out_size, void* d_ws, size_t ws_size,
                              hipStream_t stream) {
  const float* dense = (const float*)d_in[0];
  const int* oh_idx = (const int*)d_in[1];
  const int* mh_idx = (const int*)d_in[2];
  const float* oh_emb = (const float*)d_in[3];
  const float* mh_emb = (const float*)d_in[4];
  const float* cw = (const float*)d_in[5];
  const float* cb = (const float*)d_in[6];
  const float* W1 = (const float*)d_in[7];
  const float* b1 = (const float*)d_in[8];
  const float* W2 = (const float*)d_in[9];
  const float* b2 = (const float*)d_in[10];
  const float* W3 = (const float*)d_in[11];
  const float* b3 = (const float*)d_in[12];
  const float* lw = (const float*)d_in[13];
  const float* lb = (const float*)d_in[14];
  float* out = (float*)d_out;

  // workspace layout (aliases h2 over dead x0 region):
  // R1: max(x0, h2) = B*512 floats ; R2: xi ; R3: h1 ; R4: h3
  float* R1 = (float*)d_ws;                       // x0 (B*448), later h2 (B*512)
  float* xi = R1 + (size_t)B_SZ * HID2;           // B*448
  float* h1 = xi + (size_t)B_SZ * IN_DIM;         // B*1024
  float* h3 = h1 + (size_t)B_SZ * HID1;           // B*256
  float* x0 = R1;
  float* h2 = R1;

  embed_kernel<<<B_SZ / 4, 256, 0, stream>>>(dense, oh_idx, mh_idx, oh_emb, mh_emb, x0);
  cross_kernel<<<B_SZ / 4, 256, 0, stream>>>(x0, cw, cb, xi);
  {
    dim3 g(HID1 / 64, B_SZ / 64);
    gemm_kernel<true><<<g, 256, 0, stream>>>(x0, W1, b1, h1, B_SZ, HID1, IN_DIM);
  }
  {
    dim3 g(HID2 / 64, B_SZ / 64);
    gemm_kernel<true><<<g, 256, 0, stream>>>(h1, W2, b2, h2, B_SZ, HID2, HID1);
  }
  {
    dim3 g(HID3 / 64, B_SZ / 64);
    gemm_kernel<true><<<g, 256, 0, stream>>>(h2, W3, b3, h3, B_SZ, HID3, HID2);
  }
  final_kernel<<<B_SZ / 4, 256, 0, stream>>>(xi, h3, lw, lb, out);
}

// Round 2
// 149.690 us; speedup vs baseline: 3.6721x; 3.6721x over previous
//
#include <hip/hip_runtime.h>
#include <hip/hip_bf16.h>
#include <math.h>

#define B_SZ 16384
#define DENSE 64
#define N_OH 8
#define N_MH 4
#define VOCAB 100000
#define EMB 32
#define HIST 20
#define IN_DIM 448
#define HID1 1024
#define HID2 512
#define HID3 256
#define CROSS_ORDER 4

typedef __bf16 bf16_t;
typedef __bf16 bf16x8 __attribute__((ext_vector_type(8)));
typedef float f32x4 __attribute__((ext_vector_type(4)));
typedef __attribute__((address_space(1))) const void cgvoid;
typedef __attribute__((address_space(3))) void lvoid;

// ---------------- embedding + concat -> x0 fp32 (for cross) + x0b bf16 (for GEMM1)
__global__ __launch_bounds__(256) void embed_kernel(
    const float* __restrict__ dense, const int* __restrict__ oh_idx,
    const int* __restrict__ mh_idx, const float* __restrict__ oh_emb,
    const float* __restrict__ mh_emb, float* __restrict__ x0,
    bf16_t* __restrict__ x0b) {
  int wave = (blockIdx.x * blockDim.x + threadIdx.x) >> 6;
  int lane = threadIdx.x & 63;
  if (wave >= B_SZ) return;
  int row = wave;
  float* xr = x0 + (size_t)row * IN_DIM;
  bf16_t* xb = x0b + (size_t)row * IN_DIM;
  float v = dense[(size_t)row * DENSE + lane];
  xr[lane] = v;
  xb[lane] = (bf16_t)v;
#pragma unroll
  for (int r = 0; r < 4; ++r) {
    int e = lane + r * 64;
    int f = e >> 5, d = e & 31;
    int idx = oh_idx[row * N_OH + f];
    float u = oh_emb[((size_t)f * VOCAB + idx) * EMB + d];
    xr[64 + e] = u;
    xb[64 + e] = (bf16_t)u;
  }
#pragma unroll
  for (int r = 0; r < 2; ++r) {
    int e = lane + r * 64;
    int f = e >> 5, d = e & 31;
    const int* hist = mh_idx + ((size_t)row * N_MH + f) * HIST;
    float s = 0.f;
#pragma unroll
    for (int j = 0; j < HIST; ++j)
      s += mh_emb[((size_t)f * VOCAB + hist[j]) * EMB + d];
    xr[320 + e] = s;
    xb[320 + e] = (bf16_t)s;
  }
}

// ---------------- cross net (fp32): xi = x0*(xi.w_l) + b_l + xi ----------------
__global__ __launch_bounds__(256) void cross_kernel(
    const float* __restrict__ x0g, const float* __restrict__ cw,
    const float* __restrict__ cb, float* __restrict__ xig) {
  int wave = (blockIdx.x * blockDim.x + threadIdx.x) >> 6;
  int lane = threadIdx.x & 63;
  if (wave >= B_SZ) return;
  const float* xr = x0g + (size_t)wave * IN_DIM;
  float x0v[7], xiv[7];
#pragma unroll
  for (int r = 0; r < 7; ++r) {
    x0v[r] = xr[lane + r * 64];
    xiv[r] = x0v[r];
  }
  for (int l = 0; l < CROSS_ORDER; ++l) {
    const float* w = cw + l * IN_DIM;
    const float* b = cb + l * IN_DIM;
    float dot = 0.f;
#pragma unroll
    for (int r = 0; r < 7; ++r) dot += xiv[r] * w[lane + r * 64];
#pragma unroll
    for (int s = 32; s > 0; s >>= 1) dot += __shfl_xor(dot, s);
#pragma unroll
    for (int r = 0; r < 7; ++r) xiv[r] = x0v[r] * dot + b[lane + r * 64] + xiv[r];
  }
  float* xo = xig + (size_t)wave * IN_DIM;
#pragma unroll
  for (int r = 0; r < 7; ++r) xo[lane + r * 64] = xiv[r];
}

// ---------------- weight transpose + bf16 convert: W[K][N] -> Wt[N][K] ----------------
__global__ __launch_bounds__(256) void transpose_w_kernel(
    const float* __restrict__ W, bf16_t* __restrict__ Wt, int K, int N) {
  int idx = blockIdx.x * 256 + threadIdx.x;
  if (idx >= K * N) return;
  int n = idx / K, k = idx - n * K;
  Wt[idx] = (bf16_t)W[(size_t)k * N + n];
}

// ---------------- bf16 MFMA GEMM: C = relu?(A[MxK] @ Bt[NxK]^T + bias), C bf16 ----------------
// m97 structure: 128x128 tile, BK=32, 256 threads (4 waves, 2x2), 4x4 frags/wave
template <bool RELU>
__global__ __launch_bounds__(256) void gemm_bf16_kernel(
    const bf16_t* __restrict__ A, const bf16_t* __restrict__ Bt,
    const float* __restrict__ bias, bf16_t* __restrict__ C,
    int M, int N, int K) {
  __shared__ bf16_t As[128 * 32];
  __shared__ bf16_t Bs[128 * 32];
  const int tid = threadIdx.x;
  const int lane = tid & 63;
  const int wid = tid >> 6;   // 0..3
  const int wr = wid >> 1;    // wave row 0..1
  const int wc = wid & 1;     // wave col 0..1
  const int row0 = blockIdx.y * 128;
  const int col0 = blockIdx.x * 128;
  const size_t Kb = (size_t)K * 2;  // row bytes

  const int kgrp = lane >> 4;  // 0..3
  const int fr = lane & 15;

  f32x4 acc[4][4];
#pragma unroll
  for (int m = 0; m < 4; ++m)
#pragma unroll
    for (int n = 0; n < 4; ++n) acc[m][n] = (f32x4){0.f, 0.f, 0.f, 0.f};

  for (int k0 = 0; k0 < K; k0 += 32) {
    __syncthreads();  // previous compute done reading LDS
#pragma unroll
    for (int chunk = 0; chunk < 2; ++chunk) {
      // byte z within the 8KB tile this lane covers: z = chunk*4096 + wid*1024 + lane*16
      int z = chunk * 4096 + wid * 1024 + lane * 16;
      int trow = z >> 6;   // tile row (64B = 32 bf16 per row)
      int tkb = z & 63;    // byte within K-slab
      const char* gA = (const char*)A + (size_t)(row0 + trow) * Kb + (size_t)k0 * 2 + tkb;
      const char* gB = (const char*)Bt + (size_t)(col0 + trow) * Kb + (size_t)k0 * 2 + tkb;
      __builtin_amdgcn_global_load_lds((cgvoid*)gA,
          (lvoid*)((char*)As + chunk * 4096 + wid * 1024), 16, 0, 0);
      __builtin_amdgcn_global_load_lds((cgvoid*)gB,
          (lvoid*)((char*)Bs + chunk * 4096 + wid * 1024), 16, 0, 0);
    }
    __syncthreads();  // staged data visible (drains vmcnt)

    bf16x8 a[4], b[4];
#pragma unroll
    for (int m = 0; m < 4; ++m) {
      int row = wr * 64 + m * 16 + fr;
      a[m] = *reinterpret_cast<const bf16x8*>(&As[row * 32 + kgrp * 8]);
    }
#pragma unroll
    for (int n = 0; n < 4; ++n) {
      int col = wc * 64 + n * 16 + fr;
      b[n] = *reinterpret_cast<const bf16x8*>(&Bs[col * 32 + kgrp * 8]);
    }
#pragma unroll
    for (int m = 0; m < 4; ++m)
#pragma unroll
      for (int n = 0; n < 4; ++n)
        acc[m][n] = __builtin_amdgcn_mfma_f32_16x16x32_bf16(a[m], b[n], acc[m][n], 0, 0, 0);
  }

  // epilogue: C/D layout col=lane&15, row=(lane>>4)*4+reg
#pragma unroll
  for (int n = 0; n < 4; ++n) {
    int col = col0 + wc * 64 + n * 16 + fr;
    float bv = bias[col];
#pragma unroll
    for (int m = 0; m < 4; ++m) {
#pragma unroll
      for (int r = 0; r < 4; ++r) {
        int row = row0 + wr * 64 + m * 16 + kgrp * 4 + r;
        float v = acc[m][n][r] + bv;
        if (RELU) v = fmaxf(v, 0.f);
        C[(size_t)row * N + col] = (bf16_t)v;
      }
    }
  }
}

// ---------------- final head: sigmoid(concat(xi, h3) @ lin_w + lin_b) ----------------
__global__ __launch_bounds__(256) void final_kernel(
    const float* __restrict__ xi, const bf16_t* __restrict__ h3,
    const float* __restrict__ lw, const float* __restrict__ lb,
    float* __restrict__ out) {
  int wave = (blockIdx.x * blockDim.x + threadIdx.x) >> 6;
  int lane = threadIdx.x & 63;
  if (wave >= B_SZ) return;
  float s = 0.f;
  const float* xr = xi + (size_t)wave * IN_DIM;
#pragma unroll
  for (int r = 0; r < 7; ++r) s += xr[lane + r * 64] * lw[lane + r * 64];
  const bf16_t* hr = h3 + (size_t)wave * HID3;
#pragma unroll
  for (int r = 0; r < 4; ++r) s += (float)hr[lane + r * 64] * lw[448 + lane + r * 64];
#pragma unroll
  for (int t = 32; t > 0; t >>= 1) s += __shfl_xor(s, t);
  if (lane == 0) out[wave] = 1.f / (1.f + expf(-(s + lb[0])));
}

extern "C" void kernel_launch(void* const* d_in, const int* in_sizes, int n_in,
                              void* d_out, int out_size, void* d_ws, size_t ws_size,
                              hipStream_t stream) {
  const float* dense = (const float*)d_in[0];
  const int* oh_idx = (const int*)d_in[1];
  const int* mh_idx = (const int*)d_in[2];
  const float* oh_emb = (const float*)d_in[3];
  const float* mh_emb = (const float*)d_in[4];
  const float* cw = (const float*)d_in[5];
  const float* cb = (const float*)d_in[6];
  const float* W1 = (const float*)d_in[7];
  const float* b1 = (const float*)d_in[8];
  const float* W2 = (const float*)d_in[9];
  const float* b2 = (const float*)d_in[10];
  const float* W3 = (const float*)d_in[11];
  const float* b3 = (const float*)d_in[12];
  const float* lw = (const float*)d_in[13];
  const float* lb = (const float*)d_in[14];
  float* out = (float*)d_out;

  // workspace layout
  char* p = (char*)d_ws;
  float* x0 = (float*)p;            p += (size_t)B_SZ * IN_DIM * 4;   // 29.36 MB
  float* xi = (float*)p;            p += (size_t)B_SZ * IN_DIM * 4;   // 29.36 MB
  bf16_t* x0b = (bf16_t*)p;         p += (size_t)B_SZ * IN_DIM * 2;   // 14.68 MB
  bf16_t* h1b = (bf16_t*)p;         p += (size_t)B_SZ * HID1 * 2;     // 33.55 MB
  bf16_t* h2b = (bf16_t*)p;         p += (size_t)B_SZ * HID2 * 2;     // 16.78 MB
  bf16_t* h3b = (bf16_t*)p;         p += (size_t)B_SZ * HID3 * 2;     //  8.39 MB
  bf16_t* wT1 = (bf16_t*)p;         p += (size_t)HID1 * IN_DIM * 2;   //  0.92 MB
  bf16_t* wT2 = (bf16_t*)p;         p += (size_t)HID2 * HID1 * 2;     //  1.05 MB
  bf16_t* wT3 = (bf16_t*)p;         p += (size_t)HID3 * HID2 * 2;     //  0.26 MB

  transpose_w_kernel<<<(IN_DIM * HID1 + 255) / 256, 256, 0, stream>>>(W1, wT1, IN_DIM, HID1);
  transpose_w_kernel<<<(HID1 * HID2 + 255) / 256, 256, 0, stream>>>(W2, wT2, HID1, HID2);
  transpose_w_kernel<<<(HID2 * HID3 + 255) / 256, 256, 0, stream>>>(W3, wT3, HID2, HID3);

  embed_kernel<<<B_SZ / 4, 256, 0, stream>>>(dense, oh_idx, mh_idx, oh_emb, mh_emb, x0, x0b);
  cross_kernel<<<B_SZ / 4, 256, 0, stream>>>(x0, cw, cb, xi);

  {
    dim3 g(HID1 / 128, B_SZ / 128);
    gemm_bf16_kernel<true><<<g, 256, 0, stream>>>(x0b, wT1, b1, h1b, B_SZ, HID1, IN_DIM);
  }
  {
    dim3 g(HID2 / 128, B_SZ / 128);
    gemm_bf16_kernel<true><<<g, 256, 0, stream>>>(h1b, wT2, b2, h2b, B_SZ, HID2, HID1);
  }
  {
    dim3 g(HID3 / 128, B_SZ / 128);
    gemm_bf16_kernel<true><<<g, 256, 0, stream>>>(h2b, wT3, b3, h3b, B_SZ, HID3, HID2);
  }
  final_kernel<<<B_SZ / 4, 256, 0, stream>>>(xi, h3b, lw, lb, out);
}